// Round 5
// baseline (4556.702 us; speedup 1.0000x reference)
//
#include <hip/hip_runtime.h>
#include <hip/hip_bf16.h>
#include <stdint.h>

#define T_STEPS 256
#define B_SZ    256
#define NI      128
#define NR      512
#define NO      64
#define BT      16    // batch rows per group
#define HALF_R  256   // output cols per half-block
#define NGPB    4     // groups per block

typedef __attribute__((ext_vector_type(8))) short short8;
typedef __attribute__((ext_vector_type(4))) short short4v;
typedef __attribute__((ext_vector_type(4))) float f32x4;
typedef __attribute__((ext_vector_type(2))) unsigned long long u64x2;

__device__ __forceinline__ unsigned short f2bf(float f) {
    union { float f; unsigned u; } v; v.f = f;
    unsigned u = v.u;
    return (unsigned short)((u + 0x7FFFu + ((u >> 16) & 1u)) >> 16);
}

// 8 recurrent K-tiles with compile-time K-tile base (static Bh[] indices).
template<int KTB>
__device__ __forceinline__ void recur8(const unsigned char* Hbuf,
                                       const short8 (&Bh)[2][16],
                                       f32x4& acc0, f32x4& acc1,
                                       int l15, int l4, unsigned swzA) {
    #pragma unroll
    for (int kk = 0; kk < 8; ++kk) {
        const unsigned off = l15 * 1024 + (((unsigned)((KTB + kk) * 64 + l4 * 16)) ^ swzA);
        const short8 a = *(const short8*)(Hbuf + off);
        acc0 = __builtin_amdgcn_mfma_f32_16x16x32_bf16(a, Bh[0][KTB + kk], acc0, 0, 0, 0);
        acc1 = __builtin_amdgcn_mfma_f32_16x16x32_bf16(a, Bh[1][KTB + kk], acc1, 0, 0, 0);
    }
}

// ---------------------------------------------------------------------------
// proj GEMM: proj[t*B+b][n] = (bf16(inputs[t,b,:]) @ bf16(Wi)^T)[n] + bi[n]
//            + (t<4 ? noise[t,b,n] : 0).   M=65536, N=512, K=128.
// ---------------------------------------------------------------------------
__global__ __launch_bounds__(256) void proj_gemm(
    const float* __restrict__ inputs, const float* __restrict__ Wi,
    const float* __restrict__ bi, const float* __restrict__ noise,
    float* __restrict__ proj)
{
    const int mb = blockIdx.x;
    const int nb = blockIdx.y;
    const int m0 = mb * 64, n0 = nb * 128;
    const int tid = threadIdx.x, w = tid >> 6, l = tid & 63;
    const int l15 = l & 15, l4 = l >> 4;

    __shared__ __align__(16) unsigned char Al[64 * 256];    // 16 KB bf16 swizzled
    __shared__ __align__(16) unsigned char Wl[128 * 256];   // 32 KB bf16 swizzled

    #pragma unroll
    for (int j = 0; j < 8; ++j) {
        const int f = j * 256 + tid;
        const int row = f >> 5, c4 = f & 31;
        const float4 v = *(const float4*)(inputs + (size_t)(m0 + row) * NI + c4 * 4);
        short4v pk;
        pk[0] = (short)f2bf(v.x); pk[1] = (short)f2bf(v.y);
        pk[2] = (short)f2bf(v.z); pk[3] = (short)f2bf(v.w);
        *(short4v*)(&Al[row * 256 + (((unsigned)(c4 * 8)) ^ ((row & 7) << 4))]) = pk;
    }
    #pragma unroll
    for (int j = 0; j < 16; ++j) {
        const int f = j * 256 + tid;
        const int r = f >> 5, c4 = f & 31;
        const float4 v = *(const float4*)(Wi + (size_t)(n0 + r) * NI + c4 * 4);
        short4v pk;
        pk[0] = (short)f2bf(v.x); pk[1] = (short)f2bf(v.y);
        pk[2] = (short)f2bf(v.z); pk[3] = (short)f2bf(v.w);
        *(short4v*)(&Wl[r * 256 + (((unsigned)(c4 * 8)) ^ ((r & 7) << 4))]) = pk;
    }
    __syncthreads();

    f32x4 acc[8];
    #pragma unroll
    for (int nt = 0; nt < 8; ++nt) acc[nt] = (f32x4){0.f, 0.f, 0.f, 0.f};
    #pragma unroll
    for (int kt = 0; kt < 4; ++kt) {
        const short8 a = *(const short8*)(
            &Al[(w * 16 + l15) * 256 + (((unsigned)(kt * 64 + l4 * 16)) ^ ((l15 & 7) << 4))]);
        #pragma unroll
        for (int nt = 0; nt < 8; ++nt) {
            const short8 b = *(const short8*)(
                &Wl[(nt * 16 + l15) * 256 + (((unsigned)(kt * 64 + l4 * 16)) ^ ((l15 & 7) << 4))]);
            acc[nt] = __builtin_amdgcn_mfma_f32_16x16x32_bf16(a, b, acc[nt], 0, 0, 0);
        }
    }

    const int t = m0 >> 8;   // 64-row tiles never cross a t boundary
    #pragma unroll
    for (int nt = 0; nt < 8; ++nt) {
        const int n = n0 + nt * 16 + l15;
        const float bv = bi[n];
        #pragma unroll
        for (int q = 0; q < 4; ++q) {
            const int gr = m0 + w * 16 + l4 * 4 + q;
            float v = acc[nt][q] + bv;
            if (t < 4) v += noise[(size_t)gr * NR + n];
            proj[(size_t)gr * NR + n] = v;
        }
    }
}

// ---------------------------------------------------------------------------
// Persistent scan: 8 blocks x 512 threads; block = (gset = bid&3, half = bid>>2).
// Each block handles NGPB=4 independent batch groups (64 rows) for its 256-col
// half; pair (bid, bid^4). Exchange: self-flagging tagged 8B atomics via IF
// (relu => sign bits free). 4 interleaved groups hide the IF RTT under MFMA.
// ---------------------------------------------------------------------------
__global__ __launch_bounds__(512, 2) void rnn_scan(
    const float* __restrict__ Wrec,
    float* __restrict__ dout,
    unsigned long long* __restrict__ Xbuf)
{
    const int bid  = blockIdx.x;
    const int gset = bid & 3;
    const int half = bid >> 2;
    const int tid  = threadIdx.x;
    const int w    = tid >> 6;
    const int l    = tid & 63;
    const int l15  = l & 15;
    const int l4   = l >> 4;

    __shared__ __align__(16) unsigned char Hl[NGPB][2][BT * 1024];  // 128 KB

    // Wrec half -> register fragments (shared by all 4 groups)
    short8 Bh[2][16];
    #pragma unroll
    for (int ct = 0; ct < 2; ++ct) {
        const int n = half * HALF_R + w * 32 + ct * 16 + l15;
        #pragma unroll
        for (int kt = 0; kt < 16; ++kt) {
            const float* src = Wrec + (size_t)n * NR + kt * 32 + l4 * 8;
            short8 f;
            #pragma unroll
            for (int j = 0; j < 8; ++j) f[j] = (short)f2bf(src[j]);
            Bh[ct][kt] = f;
        }
    }

    float* hbuf   = dout + (size_t)NO * B_SZ;                 // proj in / h out
    float* hidout = hbuf + (size_t)T_STEPS * B_SZ * NR;

    const unsigned swzA = (unsigned)((l15 & 7) << 4);
    const int n0 = half * HALF_R + w * 32 + l15;   // ct=0 column
    const int n1 = n0 + 16;                        // ct=1 column
    const int mrow = l4 * 4;

    // prologue: acc[g] = proj[0]
    f32x4 acc0[NGPB], acc1[NGPB];
    #pragma unroll
    for (int g = 0; g < NGPB; ++g) {
        const int b0 = (gset * NGPB + g) * BT;
        #pragma unroll
        for (int q = 0; q < 4; ++q) {
            acc0[g][q] = hbuf[(size_t)(b0 + mrow + q) * NR + n0];
            acc1[g][q] = hbuf[(size_t)(b0 + mrow + q) * NR + n1];
        }
    }

    float pj0[NGPB][4], pj1[NGPB][4];

    for (int t = 0; t < T_STEPS; ++t) {
        const int p = t & 1, pn = p ^ 1;
        const int tag = ((t >> 1) & 1) ^ 1;   // parity-buffer reuse tag (1 first)
        const bool lastStep = (t == T_STEPS - 1);

        // phase A+B per group: partner recur, relu, pack+export, h store
        #pragma unroll
        for (int g = 0; g < NGPB; ++g) {
            const int grp = gset * NGPB + g;
            const int b0  = grp * BT;

            if (t > 0) {
                if (half == 0) recur8<8>(&Hl[g][p][0], Bh, acc0[g], acc1[g], l15, l4, swzA);
                else           recur8<0>(&Hl[g][p][0], Bh, acc0[g], acc1[g], l15, l4, swzA);
            }

            float v0[4], v1[4];
            #pragma unroll
            for (int q = 0; q < 4; ++q) {
                v0[q] = fmaxf(acc0[g][q], 0.f);
                v1[q] = fmaxf(acc1[g][q], 0.f);
            }

            if (lastStep) {
                #pragma unroll
                for (int q = 0; q < 4; ++q) {
                    hbuf[((size_t)t * B_SZ + b0 + mrow + q) * NR + n0] = v0[q];
                    hbuf[((size_t)t * B_SZ + b0 + mrow + q) * NR + n1] = v1[q];
                    hidout[(size_t)(b0 + mrow + q) * NR + n0] = v0[q];
                    hidout[(size_t)(b0 + mrow + q) * NR + n1] = v1[q];
                }
            } else {
                // pack 4 cols -> u64 on l%4==0 lanes; LDS own half + tagged IF export
                unsigned long long* Xh =
                    Xbuf + (size_t)grp * 4096 + (size_t)(pn * 2 + half) * 1024;
                const unsigned long long tagmask = tag ? 0x8000800080008000ULL : 0ULL;
                #pragma unroll
                for (int ct = 0; ct < 2; ++ct) {
                    #pragma unroll
                    for (int q = 0; q < 4; ++q) {
                        const float v = ct ? v1[q] : v0[q];
                        const float vo = __shfl_xor(v, 1, 64);
                        unsigned pk = (unsigned)f2bf(v) | ((unsigned)f2bf(vo) << 16);
                        const unsigned pk_hi = __shfl_xor(pk, 2, 64);
                        if ((l & 3) == 0) {
                            const int m = mrow + q;
                            const int c = w * 32 + ct * 16 + l15;     // own col, %4==0
                            const unsigned long long val =
                                (unsigned long long)pk | ((unsigned long long)pk_hi << 32);
                            const unsigned off = m * 1024 +
                                (((unsigned)(2 * (half * HALF_R + c))) ^
                                 ((unsigned)((m & 7) << 4)));
                            *(unsigned long long*)(&Hl[g][pn][off]) = val;
                            __hip_atomic_store(Xh + m * 64 + (c >> 2), val | tagmask,
                                               __ATOMIC_RELAXED, __HIP_MEMORY_SCOPE_AGENT);
                        }
                    }
                }
                // h[t] f32 store (fire and forget, after exports)
                #pragma unroll
                for (int q = 0; q < 4; ++q) {
                    hbuf[((size_t)t * B_SZ + b0 + mrow + q) * NR + n0] = v0[q];
                    hbuf[((size_t)t * B_SZ + b0 + mrow + q) * NR + n1] = v1[q];
                }
            }
        }
        if (lastStep) break;

        // barrier1: own-half LDS visible (lgkm only; exports stay in flight)
        asm volatile("s_waitcnt lgkmcnt(0)" ::: "memory");
        __builtin_amdgcn_sched_barrier(0);
        __builtin_amdgcn_s_barrier();
        __builtin_amdgcn_sched_barrier(0);

        // phase D per group: proj[t+1] prefetch + own-half recur for t+1
        #pragma unroll
        for (int g = 0; g < NGPB; ++g) {
            const int b0 = (gset * NGPB + g) * BT;
            #pragma unroll
            for (int q = 0; q < 4; ++q) {
                pj0[g][q] = hbuf[((size_t)(t + 1) * B_SZ + b0 + mrow + q) * NR + n0];
                pj1[g][q] = hbuf[((size_t)(t + 1) * B_SZ + b0 + mrow + q) * NR + n1];
            }
            acc0[g] = (f32x4){0.f, 0.f, 0.f, 0.f};
            acc1[g] = (f32x4){0.f, 0.f, 0.f, 0.f};
            if (half == 0) recur8<0>(&Hl[g][pn][0], Bh, acc0[g], acc1[g], l15, l4, swzA);
            else           recur8<8>(&Hl[g][pn][0], Bh, acc0[g], acc1[g], l15, l4, swzA);
        }

        // phase E per group: poll partner's tagged lines (poll == pull)
        #pragma unroll
        for (int g = 0; g < NGPB; ++g) {
            const int grp = gset * NGPB + g;
            const int row = tid >> 5;
            const unsigned kk = (unsigned)((2 * tid) & 63);       // even u64 index
            const unsigned long long* src =
                Xbuf + (size_t)grp * 4096 + (size_t)(pn * 2 + (half ^ 1)) * 1024 +
                row * 64 + kk;
            const unsigned et = (unsigned)tag;
            unsigned long long a, b;
            for (;;) {
                a = __hip_atomic_load(src,     __ATOMIC_RELAXED, __HIP_MEMORY_SCOPE_AGENT);
                b = __hip_atomic_load(src + 1, __ATOMIC_RELAXED, __HIP_MEMORY_SCOPE_AGENT);
                if ((((unsigned)(a >> 63)) == et) & (((unsigned)(b >> 63)) == et)) break;
            }
            if (tag) { a &= 0x7FFF7FFF7FFF7FFFULL; b &= 0x7FFF7FFF7FFF7FFFULL; }
            u64x2 dd; dd[0] = a; dd[1] = b;
            const unsigned off = row * 1024 +
                (((unsigned)((half ^ 1) * 512 + kk * 8)) ^ ((unsigned)((row & 7) << 4)));
            *(u64x2*)(&Hl[g][pn][off]) = dd;
            #pragma unroll
            for (int q = 0; q < 4; ++q) {
                acc0[g][q] += pj0[g][q];
                acc1[g][q] += pj1[g][q];
            }
        }

        // barrier2: pulled partner halves visible in LDS
        asm volatile("s_waitcnt lgkmcnt(0)" ::: "memory");
        __builtin_amdgcn_sched_barrier(0);
        __builtin_amdgcn_s_barrier();
        __builtin_amdgcn_sched_barrier(0);
    }
}

// ---------------------------------------------------------------------------
// Output head: softmax(hidden @ Wo^T + bo). 256 blocks (one batch row) x 256.
// ---------------------------------------------------------------------------
__global__ __launch_bounds__(256) void rnn_out(
    const float* __restrict__ Wo, const float* __restrict__ bo,
    float* __restrict__ dout)
{
    const float* hidden = dout + (size_t)NO * B_SZ + (size_t)T_STEPS * B_SZ * NR;
    const int b = blockIdx.x;
    const int tid = threadIdx.x, w = tid >> 6, l = tid & 63;

    __shared__ float hid[NR];
    __shared__ float lg[NO];

    if (tid < 128) {
        *(float4*)(&hid[tid * 4]) = *(const float4*)(hidden + (size_t)b * NR + tid * 4);
    }
    __syncthreads();

    #pragma unroll 1
    for (int jj = 0; jj < 16; ++jj) {
        const int j = w * 16 + jj;
        const float4* wr = (const float4*)(Wo + (size_t)j * NR + l * 8);
        const float4 a = wr[0], c = wr[1];
        const float4 h0 = *(const float4*)(&hid[l * 8]);
        const float4 h1 = *(const float4*)(&hid[l * 8 + 4]);
        float s = a.x * h0.x + a.y * h0.y + a.z * h0.z + a.w * h0.w
                + c.x * h1.x + c.y * h1.y + c.z * h1.z + c.w * h1.w;
        #pragma unroll
        for (int d = 32; d > 0; d >>= 1) s += __shfl_xor(s, d, 64);
        if (l == 0) lg[j] = s + bo[j];
    }
    __syncthreads();

    if (tid < 64) {
        const float x = lg[tid];
        float mx = x;
        #pragma unroll
        for (int d = 32; d > 0; d >>= 1) mx = fmaxf(mx, __shfl_xor(mx, d, 64));
        const float e = __expf(x - mx);
        float sum = e;
        #pragma unroll
        for (int d = 32; d > 0; d >>= 1) sum += __shfl_xor(sum, d, 64);
        dout[(size_t)b * NO + tid] = e / sum;
    }
}

extern "C" void kernel_launch(void* const* d_in, const int* in_sizes, int n_in,
                              void* d_out, int out_size, void* d_ws, size_t ws_size,
                              hipStream_t stream) {
    const float* inputs = (const float*)d_in[0];
    const float* noise  = (const float*)d_in[1];
    const float* Wi     = (const float*)d_in[2];
    const float* bi     = (const float*)d_in[3];
    const float* Wrec   = (const float*)d_in[4];
    const float* Wo     = (const float*)d_in[5];
    const float* bo     = (const float*)d_in[6];
    float* out = (float*)d_out;

    // exchange buffer: 16 grp x 2 parity x 2 half x 16 rows x 64 u64 = 512 KB
    unsigned long long* Xbuf = (unsigned long long*)d_ws;

    float* proj = out + (size_t)NO * B_SZ;   // proj lives in the h-output region

    // zero tags each launch (kills cross-run stale-tag matches; ~free)
    hipMemsetAsync(d_ws, 0, 16 * 4096 * sizeof(unsigned long long), stream);
    proj_gemm<<<dim3(1024, 4), 256, 0, stream>>>(inputs, Wi, bi, noise, proj);
    rnn_scan<<<8, 512, 0, stream>>>(Wrec, out, Xbuf);
    rnn_out<<<256, 256, 0, stream>>>(Wo, bo, out);
}

// Round 8
// 649.778 us; speedup vs baseline: 7.0127x; 7.0127x over previous
//
#include <hip/hip_runtime.h>
#include <hip/hip_bf16.h>
#include <stdint.h>

#define T_STEPS 256
#define B_SZ    256
#define NI      128
#define NR      512
#define NO      64
#define BT      16    // batch rows per group
#define HALF_R  256   // output cols per WG (half of NR)

typedef __attribute__((ext_vector_type(8))) short short8;
typedef __attribute__((ext_vector_type(4))) short short4v;
typedef __attribute__((ext_vector_type(4))) float f32x4;
typedef __attribute__((ext_vector_type(2))) unsigned long long u64x2;

__device__ __forceinline__ unsigned short f2bf(float f) {
    union { float f; unsigned u; } v; v.f = f;
    unsigned u = v.u;
    return (unsigned short)((u + 0x7FFFu + ((u >> 16) & 1u)) >> 16);
}

// 8 recurrent K-tiles with compile-time K-tile base (static Bh[] indices).
template<int KTB>
__device__ __forceinline__ void recur8(const unsigned char* Hbuf,
                                       const short8 (&Bh)[2][16],
                                       f32x4& acc0, f32x4& acc1,
                                       int l15, int l4, unsigned swzA) {
    #pragma unroll
    for (int kk = 0; kk < 8; ++kk) {
        const unsigned off = l15 * 1024 + (((unsigned)((KTB + kk) * 64 + l4 * 16)) ^ swzA);
        const short8 a = *(const short8*)(Hbuf + off);
        acc0 = __builtin_amdgcn_mfma_f32_16x16x32_bf16(a, Bh[0][KTB + kk], acc0, 0, 0, 0);
        acc1 = __builtin_amdgcn_mfma_f32_16x16x32_bf16(a, Bh[1][KTB + kk], acc1, 0, 0, 0);
    }
}

// ---------------------------------------------------------------------------
// proj GEMM: proj[t*B+b][n] = (bf16(inputs[t,b,:]) @ bf16(Wi)^T)[n] + bi[n]
//            + (t<4 ? noise[t,b,n] : 0).   M=65536, N=512, K=128.
// ---------------------------------------------------------------------------
__global__ __launch_bounds__(256) void proj_gemm(
    const float* __restrict__ inputs, const float* __restrict__ Wi,
    const float* __restrict__ bi, const float* __restrict__ noise,
    float* __restrict__ proj)
{
    const int mb = blockIdx.x;
    const int nb = blockIdx.y;
    const int m0 = mb * 64, n0 = nb * 128;
    const int tid = threadIdx.x, w = tid >> 6, l = tid & 63;
    const int l15 = l & 15, l4 = l >> 4;

    __shared__ __align__(16) unsigned char Al[64 * 256];    // 16 KB bf16 swizzled
    __shared__ __align__(16) unsigned char Wl[128 * 256];   // 32 KB bf16 swizzled

    #pragma unroll
    for (int j = 0; j < 8; ++j) {
        const int f = j * 256 + tid;
        const int row = f >> 5, c4 = f & 31;
        const float4 v = *(const float4*)(inputs + (size_t)(m0 + row) * NI + c4 * 4);
        short4v pk;
        pk[0] = (short)f2bf(v.x); pk[1] = (short)f2bf(v.y);
        pk[2] = (short)f2bf(v.z); pk[3] = (short)f2bf(v.w);
        *(short4v*)(&Al[row * 256 + (((unsigned)(c4 * 8)) ^ ((row & 7) << 4))]) = pk;
    }
    #pragma unroll
    for (int j = 0; j < 16; ++j) {
        const int f = j * 256 + tid;
        const int r = f >> 5, c4 = f & 31;
        const float4 v = *(const float4*)(Wi + (size_t)(n0 + r) * NI + c4 * 4);
        short4v pk;
        pk[0] = (short)f2bf(v.x); pk[1] = (short)f2bf(v.y);
        pk[2] = (short)f2bf(v.z); pk[3] = (short)f2bf(v.w);
        *(short4v*)(&Wl[r * 256 + (((unsigned)(c4 * 8)) ^ ((r & 7) << 4))]) = pk;
    }
    __syncthreads();

    f32x4 acc[8];
    #pragma unroll
    for (int nt = 0; nt < 8; ++nt) acc[nt] = (f32x4){0.f, 0.f, 0.f, 0.f};
    #pragma unroll
    for (int kt = 0; kt < 4; ++kt) {
        const short8 a = *(const short8*)(
            &Al[(w * 16 + l15) * 256 + (((unsigned)(kt * 64 + l4 * 16)) ^ ((l15 & 7) << 4))]);
        #pragma unroll
        for (int nt = 0; nt < 8; ++nt) {
            const short8 b = *(const short8*)(
                &Wl[(nt * 16 + l15) * 256 + (((unsigned)(kt * 64 + l4 * 16)) ^ ((l15 & 7) << 4))]);
            acc[nt] = __builtin_amdgcn_mfma_f32_16x16x32_bf16(a, b, acc[nt], 0, 0, 0);
        }
    }

    const int t = m0 >> 8;   // 64-row tiles never cross a t boundary
    #pragma unroll
    for (int nt = 0; nt < 8; ++nt) {
        const int n = n0 + nt * 16 + l15;
        const float bv = bi[n];
        #pragma unroll
        for (int q = 0; q < 4; ++q) {
            const int gr = m0 + w * 16 + l4 * 4 + q;
            float v = acc[nt][q] + bv;
            if (t < 4) v += noise[(size_t)gr * NR + n];
            proj[(size_t)gr * NR + n] = v;
        }
    }
}

// ---------------------------------------------------------------------------
// Persistent scan: 32 blocks x 512 threads; block = (grp = bid&15, half = bid>>4).
// h[t] = relu(proj[t] + h[t-1] @ Wrec^T); Wrec half register-resident (bf16).
// Cross-block exchange: self-flagging tagged 8B agent-scope atomics via IF
// (relu => bf16 sign bits carry a step-parity tag; poll == pull).
// This round: partner-line loads are PREFETCHED right after barrier1 and
// checked after own-half compute (removes re-poll RTT quantization); proj
// prefetch hoisted to loop top (~1300cy cover).
// ---------------------------------------------------------------------------
__global__ __launch_bounds__(512) void rnn_scan(
    const float* __restrict__ Wrec,
    float* __restrict__ dout,
    unsigned long long* __restrict__ Xbuf)
{
    const int bid  = blockIdx.x;
    const int grp  = bid & 15;
    const int half = bid >> 4;
    const int b0   = grp * BT;
    const int tid  = threadIdx.x;
    const int w    = tid >> 6;
    const int l    = tid & 63;
    const int l15  = l & 15;
    const int l4   = l >> 4;

    __shared__ __align__(16) unsigned char Hl[2][BT * 1024];  // 32 KB, swizzled bf16

    // Wrec half -> register fragments
    short8 Bh[2][16];
    #pragma unroll
    for (int ct = 0; ct < 2; ++ct) {
        const int n = half * HALF_R + w * 32 + ct * 16 + l15;
        #pragma unroll
        for (int kt = 0; kt < 16; ++kt) {
            const float* src = Wrec + (size_t)n * NR + kt * 32 + l4 * 8;
            short8 f;
            #pragma unroll
            for (int j = 0; j < 8; ++j) f[j] = (short)f2bf(src[j]);
            Bh[ct][kt] = f;
        }
    }

    unsigned long long* Xg = Xbuf + (size_t)grp * 4096;

    float* hbuf   = dout + (size_t)NO * B_SZ;                 // proj in / h out
    float* hidout = hbuf + (size_t)T_STEPS * B_SZ * NR;

    const unsigned swzA = (unsigned)((l15 & 7) << 4);
    const int n0 = half * HALF_R + w * 32 + l15;   // ct=0 column
    const int n1 = n0 + 16;                        // ct=1 column
    const int mrow = l4 * 4;

    // prologue: acc = proj[0]
    f32x4 acc0, acc1;
    #pragma unroll
    for (int q = 0; q < 4; ++q) {
        acc0[q] = hbuf[(size_t)(b0 + mrow + q) * NR + n0];
        acc1[q] = hbuf[(size_t)(b0 + mrow + q) * NR + n1];
    }

    float pj0[4], pj1[4];

    for (int t = 0; t < T_STEPS; ++t) {
        const int pn = (t & 1) ^ 1;
        const int tag = ((t >> 1) & 1) ^ 1;   // parity-buffer reuse tag (1 first)

        // loop top: issue proj[t+1] prefetch EARLY (~full step of cover).
        // (t=T-1 reads the hidout area: in-bounds, unused.)
        #pragma unroll
        for (int q = 0; q < 4; ++q) {
            pj0[q] = hbuf[((size_t)(t + 1) * B_SZ + b0 + mrow + q) * NR + n0];
            pj1[q] = hbuf[((size_t)(t + 1) * B_SZ + b0 + mrow + q) * NR + n1];
        }

        // phase A: partner-half recurrent contribution (exchanged h[t-1])
        if (t > 0) {
            if (half == 0) recur8<8>(&Hl[t & 1][0], Bh, acc0, acc1, l15, l4, swzA);
            else           recur8<0>(&Hl[t & 1][0], Bh, acc0, acc1, l15, l4, swzA);
        }

        float v0[4], v1[4];
        #pragma unroll
        for (int q = 0; q < 4; ++q) {
            v0[q] = fmaxf(acc0[q], 0.f);
            v1[q] = fmaxf(acc1[q], 0.f);
        }

        if (t == T_STEPS - 1) {
            #pragma unroll
            for (int q = 0; q < 4; ++q) {
                hbuf[((size_t)t * B_SZ + b0 + mrow + q) * NR + n0] = v0[q];
                hbuf[((size_t)t * B_SZ + b0 + mrow + q) * NR + n1] = v1[q];
                hidout[(size_t)(b0 + mrow + q) * NR + n0] = v0[q];
                hidout[(size_t)(b0 + mrow + q) * NR + n1] = v1[q];
            }
            break;
        }

        // phase B: pack 4 cols -> u64 on l%4==0 lanes; LDS own half (untagged)
        //          + tagged IF export (self-flagging).
        {
            unsigned long long* Xh = Xg + (size_t)(pn * 2 + half) * 1024;
            const unsigned long long tagmask = tag ? 0x8000800080008000ULL : 0ULL;
            #pragma unroll
            for (int ct = 0; ct < 2; ++ct) {
                #pragma unroll
                for (int q = 0; q < 4; ++q) {
                    const float v = ct ? v1[q] : v0[q];
                    const float vo = __shfl_xor(v, 1, 64);
                    unsigned pk = (unsigned)f2bf(v) | ((unsigned)f2bf(vo) << 16);
                    const unsigned pk_hi = __shfl_xor(pk, 2, 64);
                    if ((l & 3) == 0) {
                        const int m = mrow + q;
                        const int c = w * 32 + ct * 16 + l15;     // own-half col, %4==0
                        const unsigned long long val =
                            (unsigned long long)pk | ((unsigned long long)pk_hi << 32);
                        const unsigned off = m * 1024 +
                            (((unsigned)(2 * (half * HALF_R + c))) ^ ((unsigned)((m & 7) << 4)));
                        *(unsigned long long*)(&Hl[pn][off]) = val;
                        __hip_atomic_store(Xh + m * 64 + (c >> 2), val | tagmask,
                                           __ATOMIC_RELAXED, __HIP_MEMORY_SCOPE_AGENT);
                    }
                }
            }
        }

        // barrier1: own-half LDS visible (lgkm only; exports stay in flight)
        asm volatile("s_waitcnt lgkmcnt(0)" ::: "memory");
        __builtin_amdgcn_sched_barrier(0);
        __builtin_amdgcn_s_barrier();
        __builtin_amdgcn_sched_barrier(0);

        // phase E-prefetch: issue partner-line loads NOW; fly under phase D.
        const int prow = tid >> 5;
        const unsigned pkk = (unsigned)((2 * tid) & 63);          // even u64 index
        const unsigned long long* src =
            Xg + (size_t)(pn * 2 + (half ^ 1)) * 1024 + prow * 64 + pkk;
        unsigned long long pa = __hip_atomic_load(src,     __ATOMIC_RELAXED, __HIP_MEMORY_SCOPE_AGENT);
        unsigned long long pb = __hip_atomic_load(src + 1, __ATOMIC_RELAXED, __HIP_MEMORY_SCOPE_AGENT);
        __builtin_amdgcn_sched_barrier(0);   // pin load issue before phase D

        // phase D: h[t] store, own-half recurrent for t+1
        #pragma unroll
        for (int q = 0; q < 4; ++q) {
            hbuf[((size_t)t * B_SZ + b0 + mrow + q) * NR + n0] = v0[q];
            hbuf[((size_t)t * B_SZ + b0 + mrow + q) * NR + n1] = v1[q];
        }
        acc0 = (f32x4){0.f, 0.f, 0.f, 0.f};
        acc1 = (f32x4){0.f, 0.f, 0.f, 0.f};
        if (half == 0) recur8<0>(&Hl[pn][0], Bh, acc0, acc1, l15, l4, swzA);
        else           recur8<8>(&Hl[pn][0], Bh, acc0, acc1, l15, l4, swzA);

        // phase E: check prefetched tags; re-poll only if stale; place in LDS
        {
            const unsigned et = (unsigned)tag;
            for (;;) {
                if ((((unsigned)(pa >> 63)) == et) & (((unsigned)(pb >> 63)) == et)) break;
                pa = __hip_atomic_load(src,     __ATOMIC_RELAXED, __HIP_MEMORY_SCOPE_AGENT);
                pb = __hip_atomic_load(src + 1, __ATOMIC_RELAXED, __HIP_MEMORY_SCOPE_AGENT);
            }
            if (tag) { pa &= 0x7FFF7FFF7FFF7FFFULL; pb &= 0x7FFF7FFF7FFF7FFFULL; }
            u64x2 dd; dd[0] = pa; dd[1] = pb;
            const unsigned off = prow * 1024 +
                (((unsigned)((half ^ 1) * 512 + pkk * 8)) ^ ((unsigned)((prow & 7) << 4)));
            *(u64x2*)(&Hl[pn][off]) = dd;
        }
        #pragma unroll
        for (int q = 0; q < 4; ++q) { acc0[q] += pj0[q]; acc1[q] += pj1[q]; }

        // barrier2: pulled partner half visible in LDS
        asm volatile("s_waitcnt lgkmcnt(0)" ::: "memory");
        __builtin_amdgcn_sched_barrier(0);
        __builtin_amdgcn_s_barrier();
        __builtin_amdgcn_sched_barrier(0);
    }
}

// ---------------------------------------------------------------------------
// Output head: softmax(hidden @ Wo^T + bo). 256 blocks (one batch row) x 256.
// ---------------------------------------------------------------------------
__global__ __launch_bounds__(256) void rnn_out(
    const float* __restrict__ Wo, const float* __restrict__ bo,
    float* __restrict__ dout)
{
    const float* hidden = dout + (size_t)NO * B_SZ + (size_t)T_STEPS * B_SZ * NR;
    const int b = blockIdx.x;
    const int tid = threadIdx.x, w = tid >> 6, l = tid & 63;

    __shared__ float hid[NR];
    __shared__ float lg[NO];

    if (tid < 128) {
        *(float4*)(&hid[tid * 4]) = *(const float4*)(hidden + (size_t)b * NR + tid * 4);
    }
    __syncthreads();

    #pragma unroll 1
    for (int jj = 0; jj < 16; ++jj) {
        const int j = w * 16 + jj;
        const float4* wr = (const float4*)(Wo + (size_t)j * NR + l * 8);
        const float4 a = wr[0], c = wr[1];
        const float4 h0 = *(const float4*)(&hid[l * 8]);
        const float4 h1 = *(const float4*)(&hid[l * 8 + 4]);
        float s = a.x * h0.x + a.y * h0.y + a.z * h0.z + a.w * h0.w
                + c.x * h1.x + c.y * h1.y + c.z * h1.z + c.w * h1.w;
        #pragma unroll
        for (int d = 32; d > 0; d >>= 1) s += __shfl_xor(s, d, 64);
        if (l == 0) lg[j] = s + bo[j];
    }
    __syncthreads();

    if (tid < 64) {
        const float x = lg[tid];
        float mx = x;
        #pragma unroll
        for (int d = 32; d > 0; d >>= 1) mx = fmaxf(mx, __shfl_xor(mx, d, 64));
        const float e = __expf(x - mx);
        float sum = e;
        #pragma unroll
        for (int d = 32; d > 0; d >>= 1) sum += __shfl_xor(sum, d, 64);
        dout[(size_t)b * NO + tid] = e / sum;
    }
}

extern "C" void kernel_launch(void* const* d_in, const int* in_sizes, int n_in,
                              void* d_out, int out_size, void* d_ws, size_t ws_size,
                              hipStream_t stream) {
    const float* inputs = (const float*)d_in[0];
    const float* noise  = (const float*)d_in[1];
    const float* Wi     = (const float*)d_in[2];
    const float* bi     = (const float*)d_in[3];
    const float* Wrec   = (const float*)d_in[4];
    const float* Wo     = (const float*)d_in[5];
    const float* bo     = (const float*)d_in[6];
    float* out = (float*)d_out;

    // exchange buffer: 16 grp x 2 parity x 2 half x 16 rows x 64 u64 = 512 KB
    unsigned long long* Xbuf = (unsigned long long*)d_ws;

    float* proj = out + (size_t)NO * B_SZ;   // proj lives in the h-output region

    // zero tags each launch (kills cross-run stale-tag matches; ~free)
    (void)hipMemsetAsync(d_ws, 0, 16 * 4096 * sizeof(unsigned long long), stream);
    proj_gemm<<<dim3(1024, 4), 256, 0, stream>>>(inputs, Wi, bi, noise, proj);
    rnn_scan<<<32, 512, 0, stream>>>(Wrec, out, Xbuf);
    rnn_out<<<256, 256, 0, stream>>>(Wo, bo, out);
}